// Round 1
// 6579.829 us; speedup vs baseline: 1.0281x; 1.0281x over previous
//
#include <hip/hip_runtime.h>
#include <stdint.h>

// (B,S,V,H,O) = (64,1024,32000,1024,128). f32 inputs, f32 output.
// Persistent-LSTM v6: 256 WGs x 512 thr, 1 WG/CU (LDS 145 KB).
// vs v5 (6765 us):
//  - Barrier overhaul: per-WG PRIVATE counter (stride 128 B). 4 same-address
//    RMWs per counter per step instead of 64 -> removes ~2 us/step of LLC
//    same-address atomic serialization on the release-critical path.
//  - Poll overhaul: all 64 lanes of wave 7 poll the half's 128 WG-counters
//    (2/lane) and exit via __all -> one LLC round trip to observe release.
//  - x-phase pack f32->bf16 via v_cvt_pk_bf16_f32 (4 instr/pack2 vs ~40 of
//    integer RNE) -> x-phase stays hidden in the barrier window.
//  - x token for step s+1 loaded at the TOP of step s (before R-phase), so
//    the emb gather issues immediately at x-phase start (no serial
//    token->emb LLC round-trip chain inside the window).
// h(t) still lives in a DISTINCT buffer per timestep (hseq[t]) so readers
// use plain CACHED loads (first touch after the step barrier; sc1 stores are
// in LLC; L2 serves the 16x intra-XCD broadcast). Falls back to the 2-buffer
// L2-bypass path if ws_size is too small for 1025 buffers.
#define BB 64
#define SS 1024
#define HH 1024
#define NWG 256
#define NTHR 512
#define BBHH ((size_t)BB * HH)

typedef unsigned short u16;
typedef unsigned int u32;
typedef unsigned long long u64;
typedef short bf8 __attribute__((ext_vector_type(8)));
typedef float f32x4 __attribute__((ext_vector_type(4)));

#define WL_BYTES  131072                     // 2 mats x 32 rows x 2048 K bf16
#define RED_BYTES (16 * 16 * 17 * 4)         // 16 partial tiles, padded
#define LDS_TOTAL (WL_BYTES + RED_BYTES)     // 148480 < 160 KiB -> 1 WG/CU

#define CTR_STRIDE 32                        // u32 units -> 128 B per WG counter
#define CTR_BYTES  (NWG * CTR_STRIDE * 4)    // 32 KB

static __device__ __forceinline__ u16 f2bf(float f) {
    union { float f; uint32_t u; } v; v.f = f;
    return (u16)((v.u + 0x7fffu + ((v.u >> 16) & 1u)) >> 16);  // RNE
}
static __device__ __forceinline__ float bf2f(u16 u) {
    union { uint32_t u; float f; } v; v.u = ((uint32_t)u) << 16; return v.f;
}
static __device__ __forceinline__ float fsig(float x) {
    return __builtin_amdgcn_rcpf(1.f + __expf(-x));
}
static __device__ __forceinline__ float ftanh(float x) {
    return 1.f - 2.f * __builtin_amdgcn_rcpf(1.f + __expf(2.f * x));
}
// HW packed f32->bf16 (RNE), schedulable (non-volatile asm).
static __device__ __forceinline__ bf8 pack2(f32x4 a, f32x4 b) {
    union { u32 w[4]; bf8 v; } r;
    asm("v_cvt_pk_bf16_f32 %0, %1, %2" : "=v"(r.w[0]) : "v"(a[0]), "v"(a[1]));
    asm("v_cvt_pk_bf16_f32 %0, %1, %2" : "=v"(r.w[1]) : "v"(a[2]), "v"(a[3]));
    asm("v_cvt_pk_bf16_f32 %0, %1, %2" : "=v"(r.w[2]) : "v"(b[0]), "v"(b[1]));
    asm("v_cvt_pk_bf16_f32 %0, %1, %2" : "=v"(r.w[3]) : "v"(b[2]), "v"(b[3]));
    return r.v;
}

// h0 f32 -> hseq[0] (bf16); zero barrier counters.
__global__ __launch_bounds__(256) void init_misc(
    const float* __restrict__ h0, u16* __restrict__ hseq0, u32* __restrict__ ctr)
{
    int i = blockIdx.x * 256 + threadIdx.x;
    if (i < BB * HH) hseq0[i] = f2bf(h0[i]);
    if (i < NWG * CTR_STRIDE) ctr[i] = 0u;
}

__global__ __launch_bounds__(NTHR, 1) void lstm_persist(
    const int*   __restrict__ x,     // [B,S]
    const float* __restrict__ emb,   // [V,H]
    const float* __restrict__ Wih,   // [4H,H]
    const float* __restrict__ Whh,   // [4H,H]
    const float* __restrict__ bih,   // [4H]
    const float* __restrict__ bhh,   // [4H]
    const float* __restrict__ c0,    // [B,H]
    u16*         __restrict__ hseq,  // ws: nbuf x [B,H] bf16 (hseq[0] = h0)
    u32*         __restrict__ ctr,   // ws: 256 per-WG counters, stride 32 u32
    int cached)                      // 1: distinct buffer per step (cached reads)
{
    extern __shared__ char smem[];
    u16* WL = (u16*)smem;            // chunk ((mat*2+nh)*32+kb)*512 + lane*8
    float (*red)[16][17] = (float (*)[16][17])(smem + WL_BYTES);

    const int tid  = threadIdx.x;
    const int wv   = tid >> 6;
    const int lane = tid & 63;
    const int n16  = lane & 15;
    const int quad = lane >> 4;
    // XCD-aware swizzle (XCD = blockIdx%8 heuristic): XCDs 0-3 get bh=0,
    // 4-7 get bh=1 -> each XCD's L2 caches only ONE half's h (64 KB/step).
    const int bh   = (blockIdx.x & 7) >> 2;
    const int cb   = ((blockIdx.x >> 3) << 2) | (blockIdx.x & 3);  // 0..127

    // ---- one-time: stage W slice into LDS (f32 -> bf16, B-frag order) ----
    for (int u = tid; u < 8192; u += NTHR) {
        int ln  = u & 63;
        int kb  = (u >> 6) & 31;
        int nh  = (u >> 11) & 1;
        int mat = u >> 12;
        int rl  = nh * 16 + (ln & 15);
        int q   = rl >> 3, j = rl & 7;
        const float* src = (mat ? Whh : Wih)
                         + (size_t)(q * HH + cb * 8 + j) * HH + kb * 32 + (ln >> 4) * 8;
        u16* dst = WL + (size_t)u * 8;
        #pragma unroll
        for (int e = 0; e < 8; ++e) dst[e] = f2bf(src[e]);
    }

    // ---- epilogue-thread constants (tid<256 owns one (b,ch)) ----
    float bias[4] = {0.f, 0.f, 0.f, 0.f};
    float creg = 0.f;
    int eb = 0, ech = 0;
    if (tid < 256) {
        int mhe = tid >> 7, m = (tid >> 3) & 15, j = tid & 7;
        eb  = bh * 32 + mhe * 16 + m;
        ech = cb * 8 + j;
        #pragma unroll
        for (int q = 0; q < 4; ++q) bias[q] = bih[q * HH + ech] + bhh[q * HH + ech];
    }

    // wave role: mh (batch 16-half), kh (K quarter of 1024); both nh per wave
    const int mh = wv >> 2, kh = wv & 3;
    const int ab = bh * 32 + mh * 16 + n16;   // A batch row (m = lane&15)
    const u16* WLx0 = WL + ((size_t)(0 * 32 + kh * 8) * 512) + lane * 8;  // Wih nh=0
    const u16* WLx1 = WL + ((size_t)(1 * 32 + kh * 8) * 512) + lane * 8;  // Wih nh=1
    const u16* WLr0 = WL + ((size_t)(2 * 32 + kh * 8) * 512) + lane * 8;  // Whh nh=0
    const u16* WLr1 = WL + ((size_t)(3 * 32 + kh * 8) * 512) + lane * 8;  // Whh nh=1

    __syncthreads();  // WL ready

    // per-WG private counter (one 128 B line each; 4 adds/step, no cross-WG
    // same-address contention).
    u32* myctr = ctr + (size_t)(bh * 128 + cb) * CTR_STRIDE;
    // poll targets for wave 7: the half's 128 WG counters, 2 per lane
    u32* poll0 = ctr + (size_t)(bh * 128 + lane) * CTR_STRIDE;
    u32* poll1 = ctr + (size_t)(bh * 128 + 64 + lane) * CTR_STRIDE;

    // gx partials for the CURRENT step, in regs across the barrier.
    f32x4 accx0, accx1;
    auto xphase = [&](int xr) {      // direct cached emb loads (barrier window)
        const float* ep = emb + (size_t)xr * HH + kh * 256 + quad * 8;
        f32x4 a0 = {0.f, 0.f, 0.f, 0.f}, a1 = {0.f, 0.f, 0.f, 0.f};
        #pragma unroll
        for (int t = 0; t < 8; ++t) {
            bf8 av = pack2(*(const f32x4*)(ep + t * 32), *(const f32x4*)(ep + t * 32 + 4));
            bf8 b0 = *(const bf8*)(WLx0 + t * 512);
            bf8 b1 = *(const bf8*)(WLx1 + t * 512);
            a0 = __builtin_amdgcn_mfma_f32_16x16x32_bf16(av, b0, a0, 0, 0, 0);
            a1 = __builtin_amdgcn_mfma_f32_16x16x32_bf16(av, b1, a1, 0, 0, 0);
        }
        accx0 = a0; accx1 = a1;
    };
    xphase(x[(size_t)ab * SS + 0]);

    for (int s = 0; s < SS; ++s) {
        const bool more = (s + 1 < SS);
        const int  ri   = cached ? s : (s & 1);          // read buffer index
        const int  wi   = cached ? (s + 1) : ((s + 1) & 1);  // write buffer index

        // issue next token load EARLY (used ~2000 cy later in xphase)
        int xr_next = 0;
        if (more) xr_next = x[(size_t)ab * SS + (s + 1)];

        // ---- R-phase: acc = gx + h[s].W_hh^T ----
        {
            const u16* hp = hseq + (size_t)ri * BBHH
                          + (size_t)ab * HH + kh * 256 + quad * 8;
            bf8 hv[8];
            if (cached) {                 // plain dwordx4, L1/L2-cacheable
                #pragma unroll
                for (int t = 0; t < 8; ++t) hv[t] = *(const bf8*)(hp + t * 32);
            } else {                      // fallback: L2-bypass atomic loads
                #pragma unroll
                for (int t = 0; t < 8; ++t) {
                    union { u64 q[2]; bf8 v; } av;
                    av.q[0] = __hip_atomic_load((const u64*)(hp + t * 32),
                                  __ATOMIC_RELAXED, __HIP_MEMORY_SCOPE_AGENT);
                    av.q[1] = __hip_atomic_load((const u64*)(hp + t * 32 + 4),
                                  __ATOMIC_RELAXED, __HIP_MEMORY_SCOPE_AGENT);
                    hv[t] = av.v;
                }
            }
            f32x4 a0 = accx0, a1 = accx1;
            #pragma unroll
            for (int t = 0; t < 8; ++t) {
                bf8 b0 = *(const bf8*)(WLr0 + t * 512);
                bf8 b1 = *(const bf8*)(WLr1 + t * 512);
                a0 = __builtin_amdgcn_mfma_f32_16x16x32_bf16(hv[t], b0, a0, 0, 0, 0);
                a1 = __builtin_amdgcn_mfma_f32_16x16x32_bf16(hv[t], b1, a1, 0, 0, 0);
            }
            const int w2 = wv * 2;     // 16 partial tiles: (mh*4+kh)*2 + nh
            #pragma unroll
            for (int r = 0; r < 4; ++r) {   // C/D: col(n)=lane&15, row(m)=quad*4+r
                red[w2 + 0][quad * 4 + r][n16] = a0[r];
                red[w2 + 1][quad * 4 + r][n16] = a1[r];
            }
        }
        __syncthreads();  // sync1: red ready

        // ---- epilogue (waves 0-3): gates -> c,h ; h packed u64, sc1 stores ----
        if (tid < 256) {
            const int mhe = tid >> 7, m = (tid >> 3) & 15, j = tid & 7;
            float g[4];
            #pragma unroll
            for (int q = 0; q < 4; ++q) {
                const int nh = q >> 1, nn = (q & 1) * 8 + j;
                float acc = bias[q];
                #pragma unroll
                for (int k = 0; k < 4; ++k)
                    acc += red[(mhe * 4 + k) * 2 + nh][m][nn];
                g[q] = acc;
            }
            float ig = fsig(g[0]);
            float fg = fsig(g[1]);
            float gv = ftanh(g[2]);
            float og = fsig(g[3]);
            float cp = (s == 0) ? c0[(size_t)eb * HH + ech] : creg;
            float cn = fg * cp + ig * gv;
            creg = cn;
            u32 hv = f2bf(og * ftanh(cn));
            u32 p1 = (u32)__shfl_xor((int)hv, 1);
            u32 w  = hv | (p1 << 16);
            u32 wp = (u32)__shfl_xor((int)w, 2);
            if ((tid & 3) == 0) {     // j in {0,4}: one u64 = 4 channels
                u64 dv = (u64)w | ((u64)wp << 32);
                u16* hd = hseq + (size_t)wi * BBHH + (size_t)eb * HH + ech;
                __hip_atomic_store((u64*)hd, dv,
                                   __ATOMIC_RELAXED, __HIP_MEMORY_SCOPE_AGENT);
            }
        }

        if (more) {
            // per-wave arrive: wait own stores' acks (vmcnt is per-wave),
            // then ONE relaxed RMW to this WG's PRIVATE counter.
            if (wv < 4) {
                __builtin_amdgcn_s_waitcnt(0);
                if (lane == 0)
                    __hip_atomic_fetch_add(myctr, 1u, __ATOMIC_RELAXED,
                                           __HIP_MEMORY_SCOPE_AGENT);
            }
            // X-phase for s+1 (emb loads + MFMA hidden in the barrier window)
            xphase(xr_next);
            // wave 7: 64 lanes poll the half's 128 WG counters in parallel
            if (wv == 7) {
                const u32 tgt = 4u * (u32)(s + 1);
                for (;;) {
                    u32 a = __hip_atomic_load(poll0, __ATOMIC_RELAXED,
                                              __HIP_MEMORY_SCOPE_AGENT);
                    u32 b = __hip_atomic_load(poll1, __ATOMIC_RELAXED,
                                              __HIP_MEMORY_SCOPE_AGENT);
                    if (__all((a >= tgt) && (b >= tgt))) break;
                    __builtin_amdgcn_s_sleep(1);
                }
            }
            __syncthreads();  // sync3: all waves released together
            // no acquire-invalidate: cached path reads never-before-touched
            // addresses; bypass path reads skip L1/L2 entirely.
        }
    }
}

// out[b][o] = h_last[b] . fc_W[o] + fc_b[o]; f32 out.
__global__ __launch_bounds__(128) void fc_kernel(
    const u16*   __restrict__ h,
    const float* __restrict__ fcW,
    const float* __restrict__ fcb,
    float*       __restrict__ out)
{
    int b = blockIdx.x;
    int o = threadIdx.x;
    const u16*   hp = h + (size_t)b * HH;
    const float* wp = fcW + (size_t)o * HH;
    float acc = 0.f;
    for (int k = 0; k < HH; k += 8) {
        bf8 hv = *(const bf8*)(hp + k);
        #pragma unroll
        for (int e = 0; e < 8; ++e)
            acc += bf2f((u16)hv[e]) * wp[k + e];
    }
    out[(size_t)b * 128 + o] = acc + fcb[o];
}

extern "C" void kernel_launch(void* const* d_in, const int* in_sizes, int n_in,
                              void* d_out, int out_size, void* d_ws, size_t ws_size,
                              hipStream_t stream) {
    const int*   x   = (const int*)d_in[0];
    const float* emb = (const float*)d_in[1];
    const float* Wih = (const float*)d_in[2];
    const float* Whh = (const float*)d_in[3];
    const float* bih = (const float*)d_in[4];
    const float* bhh = (const float*)d_in[5];
    const float* fcW = (const float*)d_in[6];
    const float* fcb = (const float*)d_in[7];
    const float* h0  = (const float*)d_in[8];
    const float* c0  = (const float*)d_in[9];

    const size_t hbytes = BBHH * sizeof(u16);                 // 128 KB per buffer
    const size_t need   = (size_t)(SS + 1) * hbytes + CTR_BYTES;  // ~134.4 MB
    const int    cached = (ws_size >= need) ? 1 : 0;
    const int    nbuf   = cached ? (SS + 1) : 2;

    u16* hseq = (u16*)d_ws;
    u32* ctr  = (u32*)((char*)d_ws + (size_t)nbuf * hbytes);

    hipFuncSetAttribute((const void*)lstm_persist,
                        hipFuncAttributeMaxDynamicSharedMemorySize, LDS_TOTAL);

    init_misc<<<256, 256, 0, stream>>>(h0, hseq, ctr);
    lstm_persist<<<NWG, NTHR, LDS_TOTAL, stream>>>(x, emb, Wih, Whh, bih, bhh,
                                                   c0, hseq, ctr, cached);
    fc_kernel<<<BB, 128, 0, stream>>>(hseq + (size_t)(cached ? SS : 0) * BBHH,
                                      fcW, fcb, (float*)d_out);
}

// Round 2
// 5043.658 us; speedup vs baseline: 1.3412x; 1.3046x over previous
//
#include <hip/hip_runtime.h>
#include <stdint.h>

// (B,S,V,H,O) = (64,1024,32000,1024,128). f32 inputs, f32 output.
// Persistent-LSTM v7: 256 WGs x 512 thr, 1 WG/CU (LDS 145 KB).
// vs v6 (6580 us): x-phase reads a PRE-CONVERTED bf16 emb table from ws.
//  Theory: step time is per-XCD L2-BW bound on the emb broadcast (each XCD's
//  32 WGs re-read the same 32 token rows = 4 MB/step/XCD in f32). bf16 table
//  halves that (and kills the f32->bf16 pack VALU in the window). MFMA input
//  bits are IDENTICAL (same RNE cvt_pk, done once in emb_cvt) -> absmax
//  unchanged. Falls back to f32 path if ws too small (need 134.4 -> 198.9 MB).
// Barrier protocol unchanged from v6 (per-WG private counters, 64-lane poll).
#define BB 64
#define SS 1024
#define VV 32000
#define HH 1024
#define NWG 256
#define NTHR 512
#define BBHH ((size_t)BB * HH)

typedef unsigned short u16;
typedef unsigned int u32;
typedef unsigned long long u64;
typedef short bf8 __attribute__((ext_vector_type(8)));
typedef float f32x4 __attribute__((ext_vector_type(4)));

#define WL_BYTES  131072                     // 2 mats x 32 rows x 2048 K bf16
#define RED_BYTES (16 * 16 * 17 * 4)         // 16 partial tiles, padded
#define LDS_TOTAL (WL_BYTES + RED_BYTES)     // 148480 < 160 KiB -> 1 WG/CU

#define CTR_STRIDE 32                        // u32 units -> 128 B per WG counter
#define CTR_BYTES  (NWG * CTR_STRIDE * 4)    // 32 KB

static __device__ __forceinline__ u16 f2bf(float f) {
    union { float f; uint32_t u; } v; v.f = f;
    return (u16)((v.u + 0x7fffu + ((v.u >> 16) & 1u)) >> 16);  // RNE
}
static __device__ __forceinline__ float bf2f(u16 u) {
    union { uint32_t u; float f; } v; v.u = ((uint32_t)u) << 16; return v.f;
}
static __device__ __forceinline__ float fsig(float x) {
    return __builtin_amdgcn_rcpf(1.f + __expf(-x));
}
static __device__ __forceinline__ float ftanh(float x) {
    return 1.f - 2.f * __builtin_amdgcn_rcpf(1.f + __expf(2.f * x));
}
// HW packed f32->bf16 (RNE), schedulable (non-volatile asm).
static __device__ __forceinline__ bf8 pack2(f32x4 a, f32x4 b) {
    union { u32 w[4]; bf8 v; } r;
    asm("v_cvt_pk_bf16_f32 %0, %1, %2" : "=v"(r.w[0]) : "v"(a[0]), "v"(a[1]));
    asm("v_cvt_pk_bf16_f32 %0, %1, %2" : "=v"(r.w[1]) : "v"(a[2]), "v"(a[3]));
    asm("v_cvt_pk_bf16_f32 %0, %1, %2" : "=v"(r.w[2]) : "v"(b[0]), "v"(b[1]));
    asm("v_cvt_pk_bf16_f32 %0, %1, %2" : "=v"(r.w[3]) : "v"(b[2]), "v"(b[3]));
    return r.v;
}

// emb f32 -> bf16 table in ws (RNE, same bits the MFMA consumed before).
__global__ __launch_bounds__(256) void emb_cvt(
    const float* __restrict__ emb, u16* __restrict__ dst)
{
    size_t i = ((size_t)blockIdx.x * 256 + threadIdx.x) * 8;
    f32x4 a = *(const f32x4*)(emb + i);
    f32x4 b = *(const f32x4*)(emb + i + 4);
    *(bf8*)(dst + i) = pack2(a, b);
}

// h0 f32 -> hseq[0] (bf16); zero barrier counters.
__global__ __launch_bounds__(256) void init_misc(
    const float* __restrict__ h0, u16* __restrict__ hseq0, u32* __restrict__ ctr)
{
    int i = blockIdx.x * 256 + threadIdx.x;
    if (i < BB * HH) hseq0[i] = f2bf(h0[i]);
    if (i < NWG * CTR_STRIDE) ctr[i] = 0u;
}

__global__ __launch_bounds__(NTHR, 1) void lstm_persist(
    const int*   __restrict__ x,      // [B,S]
    const float* __restrict__ emb,    // [V,H] f32
    const u16*   __restrict__ embbf,  // ws: [V,H] bf16 (valid iff embf)
    const float* __restrict__ Wih,    // [4H,H]
    const float* __restrict__ Whh,    // [4H,H]
    const float* __restrict__ bih,    // [4H]
    const float* __restrict__ bhh,    // [4H]
    const float* __restrict__ c0,     // [B,H]
    u16*         __restrict__ hseq,   // ws: nbuf x [B,H] bf16 (hseq[0] = h0)
    u32*         __restrict__ ctr,    // ws: 256 per-WG counters, stride 32 u32
    int cached,                       // 1: distinct h buffer per step
    int embf)                         // 1: bf16 emb table available
{
    extern __shared__ char smem[];
    u16* WL = (u16*)smem;            // chunk ((mat*2+nh)*32+kb)*512 + lane*8
    float (*red)[16][17] = (float (*)[16][17])(smem + WL_BYTES);

    const int tid  = threadIdx.x;
    const int wv   = tid >> 6;
    const int lane = tid & 63;
    const int n16  = lane & 15;
    const int quad = lane >> 4;
    // XCD-aware swizzle (XCD = blockIdx%8 heuristic): XCDs 0-3 get bh=0,
    // 4-7 get bh=1 -> each XCD's L2 caches only ONE half's h + emb rows.
    const int bh   = (blockIdx.x & 7) >> 2;
    const int cb   = ((blockIdx.x >> 3) << 2) | (blockIdx.x & 3);  // 0..127

    // ---- one-time: stage W slice into LDS (f32 -> bf16, B-frag order) ----
    for (int u = tid; u < 8192; u += NTHR) {
        int ln  = u & 63;
        int kb  = (u >> 6) & 31;
        int nh  = (u >> 11) & 1;
        int mat = u >> 12;
        int rl  = nh * 16 + (ln & 15);
        int q   = rl >> 3, j = rl & 7;
        const float* src = (mat ? Whh : Wih)
                         + (size_t)(q * HH + cb * 8 + j) * HH + kb * 32 + (ln >> 4) * 8;
        u16* dst = WL + (size_t)u * 8;
        #pragma unroll
        for (int e = 0; e < 8; ++e) dst[e] = f2bf(src[e]);
    }

    // ---- epilogue-thread constants (tid<256 owns one (b,ch)) ----
    float bias[4] = {0.f, 0.f, 0.f, 0.f};
    float creg = 0.f;
    int eb = 0, ech = 0;
    if (tid < 256) {
        int mhe = tid >> 7, m = (tid >> 3) & 15, j = tid & 7;
        eb  = bh * 32 + mhe * 16 + m;
        ech = cb * 8 + j;
        #pragma unroll
        for (int q = 0; q < 4; ++q) bias[q] = bih[q * HH + ech] + bhh[q * HH + ech];
    }

    // wave role: mh (batch 16-half), kh (K quarter of 1024); both nh per wave
    const int mh = wv >> 2, kh = wv & 3;
    const int ab = bh * 32 + mh * 16 + n16;   // A batch row (m = lane&15)
    const u16* WLx0 = WL + ((size_t)(0 * 32 + kh * 8) * 512) + lane * 8;  // Wih nh=0
    const u16* WLx1 = WL + ((size_t)(1 * 32 + kh * 8) * 512) + lane * 8;  // Wih nh=1
    const u16* WLr0 = WL + ((size_t)(2 * 32 + kh * 8) * 512) + lane * 8;  // Whh nh=0
    const u16* WLr1 = WL + ((size_t)(3 * 32 + kh * 8) * 512) + lane * 8;  // Whh nh=1

    __syncthreads();  // WL ready

    // per-WG private counter (one 128 B line each; 4 adds/step, no cross-WG
    // same-address contention).
    u32* myctr = ctr + (size_t)(bh * 128 + cb) * CTR_STRIDE;
    // poll targets for wave 7: the half's 128 WG counters, 2 per lane
    u32* poll0 = ctr + (size_t)(bh * 128 + lane) * CTR_STRIDE;
    u32* poll1 = ctr + (size_t)(bh * 128 + 64 + lane) * CTR_STRIDE;

    // gx partials for the CURRENT step, in regs across the barrier.
    f32x4 accx0, accx1;
    auto xphase = [&](int xr) {      // direct cached emb loads (barrier window)
        f32x4 a0 = {0.f, 0.f, 0.f, 0.f}, a1 = {0.f, 0.f, 0.f, 0.f};
        if (embf) {
            // bf16 table: half the bytes, half the load instrs, zero cvt VALU
            const u16* ep = embbf + (size_t)xr * HH + kh * 256 + quad * 8;
            #pragma unroll
            for (int t = 0; t < 8; ++t) {
                bf8 av = *(const bf8*)(ep + t * 32);
                bf8 b0 = *(const bf8*)(WLx0 + t * 512);
                bf8 b1 = *(const bf8*)(WLx1 + t * 512);
                a0 = __builtin_amdgcn_mfma_f32_16x16x32_bf16(av, b0, a0, 0, 0, 0);
                a1 = __builtin_amdgcn_mfma_f32_16x16x32_bf16(av, b1, a1, 0, 0, 0);
            }
        } else {
            const float* ep = emb + (size_t)xr * HH + kh * 256 + quad * 8;
            #pragma unroll
            for (int t = 0; t < 8; ++t) {
                bf8 av = pack2(*(const f32x4*)(ep + t * 32),
                               *(const f32x4*)(ep + t * 32 + 4));
                bf8 b0 = *(const bf8*)(WLx0 + t * 512);
                bf8 b1 = *(const bf8*)(WLx1 + t * 512);
                a0 = __builtin_amdgcn_mfma_f32_16x16x32_bf16(av, b0, a0, 0, 0, 0);
                a1 = __builtin_amdgcn_mfma_f32_16x16x32_bf16(av, b1, a1, 0, 0, 0);
            }
        }
        accx0 = a0; accx1 = a1;
    };
    xphase(x[(size_t)ab * SS + 0]);

    for (int s = 0; s < SS; ++s) {
        const bool more = (s + 1 < SS);
        const int  ri   = cached ? s : (s & 1);          // read buffer index
        const int  wi   = cached ? (s + 1) : ((s + 1) & 1);  // write buffer index

        // issue next token load EARLY (used ~2000 cy later in xphase)
        int xr_next = 0;
        if (more) xr_next = x[(size_t)ab * SS + (s + 1)];

        // ---- R-phase: acc = gx + h[s].W_hh^T ----
        {
            const u16* hp = hseq + (size_t)ri * BBHH
                          + (size_t)ab * HH + kh * 256 + quad * 8;
            bf8 hv[8];
            if (cached) {                 // plain dwordx4, L1/L2-cacheable
                #pragma unroll
                for (int t = 0; t < 8; ++t) hv[t] = *(const bf8*)(hp + t * 32);
            } else {                      // fallback: L2-bypass atomic loads
                #pragma unroll
                for (int t = 0; t < 8; ++t) {
                    union { u64 q[2]; bf8 v; } av;
                    av.q[0] = __hip_atomic_load((const u64*)(hp + t * 32),
                                  __ATOMIC_RELAXED, __HIP_MEMORY_SCOPE_AGENT);
                    av.q[1] = __hip_atomic_load((const u64*)(hp + t * 32 + 4),
                                  __ATOMIC_RELAXED, __HIP_MEMORY_SCOPE_AGENT);
                    hv[t] = av.v;
                }
            }
            f32x4 a0 = accx0, a1 = accx1;
            #pragma unroll
            for (int t = 0; t < 8; ++t) {
                bf8 b0 = *(const bf8*)(WLr0 + t * 512);
                bf8 b1 = *(const bf8*)(WLr1 + t * 512);
                a0 = __builtin_amdgcn_mfma_f32_16x16x32_bf16(hv[t], b0, a0, 0, 0, 0);
                a1 = __builtin_amdgcn_mfma_f32_16x16x32_bf16(hv[t], b1, a1, 0, 0, 0);
            }
            const int w2 = wv * 2;     // 16 partial tiles: (mh*4+kh)*2 + nh
            #pragma unroll
            for (int r = 0; r < 4; ++r) {   // C/D: col(n)=lane&15, row(m)=quad*4+r
                red[w2 + 0][quad * 4 + r][n16] = a0[r];
                red[w2 + 1][quad * 4 + r][n16] = a1[r];
            }
        }
        __syncthreads();  // sync1: red ready

        // ---- epilogue (waves 0-3): gates -> c,h ; h packed u64, sc1 stores ----
        if (tid < 256) {
            const int mhe = tid >> 7, m = (tid >> 3) & 15, j = tid & 7;
            float g[4];
            #pragma unroll
            for (int q = 0; q < 4; ++q) {
                const int nh = q >> 1, nn = (q & 1) * 8 + j;
                float acc = bias[q];
                #pragma unroll
                for (int k = 0; k < 4; ++k)
                    acc += red[(mhe * 4 + k) * 2 + nh][m][nn];
                g[q] = acc;
            }
            float ig = fsig(g[0]);
            float fg = fsig(g[1]);
            float gv = ftanh(g[2]);
            float og = fsig(g[3]);
            float cp = (s == 0) ? c0[(size_t)eb * HH + ech] : creg;
            float cn = fg * cp + ig * gv;
            creg = cn;
            u32 hv = f2bf(og * ftanh(cn));
            u32 p1 = (u32)__shfl_xor((int)hv, 1);
            u32 w  = hv | (p1 << 16);
            u32 wp = (u32)__shfl_xor((int)w, 2);
            if ((tid & 3) == 0) {     // j in {0,4}: one u64 = 4 channels
                u64 dv = (u64)w | ((u64)wp << 32);
                u16* hd = hseq + (size_t)wi * BBHH + (size_t)eb * HH + ech;
                __hip_atomic_store((u64*)hd, dv,
                                   __ATOMIC_RELAXED, __HIP_MEMORY_SCOPE_AGENT);
            }
        }

        if (more) {
            // per-wave arrive: wait own stores' acks (vmcnt is per-wave),
            // then ONE relaxed RMW to this WG's PRIVATE counter.
            if (wv < 4) {
                __builtin_amdgcn_s_waitcnt(0);
                if (lane == 0)
                    __hip_atomic_fetch_add(myctr, 1u, __ATOMIC_RELAXED,
                                           __HIP_MEMORY_SCOPE_AGENT);
            }
            // X-phase for s+1 (emb loads + MFMA hidden in the barrier window)
            xphase(xr_next);
            // wave 7: 64 lanes poll the half's 128 WG counters in parallel
            if (wv == 7) {
                const u32 tgt = 4u * (u32)(s + 1);
                for (;;) {
                    u32 a = __hip_atomic_load(poll0, __ATOMIC_RELAXED,
                                              __HIP_MEMORY_SCOPE_AGENT);
                    u32 b = __hip_atomic_load(poll1, __ATOMIC_RELAXED,
                                              __HIP_MEMORY_SCOPE_AGENT);
                    if (__all((a >= tgt) && (b >= tgt))) break;
                    __builtin_amdgcn_s_sleep(1);
                }
            }
            __syncthreads();  // sync3: all waves released together
            // no acquire-invalidate: cached path reads never-before-touched
            // addresses; bypass path reads skip L1/L2 entirely.
        }
    }
}

// out[b][o] = h_last[b] . fc_W[o] + fc_b[o]; f32 out.
__global__ __launch_bounds__(128) void fc_kernel(
    const u16*   __restrict__ h,
    const float* __restrict__ fcW,
    const float* __restrict__ fcb,
    float*       __restrict__ out)
{
    int b = blockIdx.x;
    int o = threadIdx.x;
    const u16*   hp = h + (size_t)b * HH;
    const float* wp = fcW + (size_t)o * HH;
    float acc = 0.f;
    for (int k = 0; k < HH; k += 8) {
        bf8 hv = *(const bf8*)(hp + k);
        #pragma unroll
        for (int e = 0; e < 8; ++e)
            acc += bf2f((u16)hv[e]) * wp[k + e];
    }
    out[(size_t)b * 128 + o] = acc + fcb[o];
}

extern "C" void kernel_launch(void* const* d_in, const int* in_sizes, int n_in,
                              void* d_out, int out_size, void* d_ws, size_t ws_size,
                              hipStream_t stream) {
    const int*   x   = (const int*)d_in[0];
    const float* emb = (const float*)d_in[1];
    const float* Wih = (const float*)d_in[2];
    const float* Whh = (const float*)d_in[3];
    const float* bih = (const float*)d_in[4];
    const float* bhh = (const float*)d_in[5];
    const float* fcW = (const float*)d_in[6];
    const float* fcb = (const float*)d_in[7];
    const float* h0  = (const float*)d_in[8];
    const float* c0  = (const float*)d_in[9];

    const size_t hbytes    = BBHH * sizeof(u16);               // 128 KB per buffer
    const size_t base_need = (size_t)(SS + 1) * hbytes + CTR_BYTES;   // ~134.4 MB
    const size_t emb_bytes = (size_t)VV * HH * sizeof(u16);    // 64 MB
    const size_t full_need = base_need + emb_bytes;            // ~198.9 MB

    const int cached = (ws_size >= base_need) ? 1 : 0;
    const int embf   = (ws_size >= full_need) ? 1 : 0;
    const int nbuf   = cached ? (SS + 1) : 2;

    u16* hseq  = (u16*)d_ws;
    u32* ctr   = (u32*)((char*)d_ws + (size_t)nbuf * hbytes);
    u16* embbf = (u16*)((char*)d_ws + (size_t)(SS + 1) * hbytes + CTR_BYTES);

    hipFuncSetAttribute((const void*)lstm_persist,
                        hipFuncAttributeMaxDynamicSharedMemorySize, LDS_TOTAL);

    if (embf)
        emb_cvt<<<VV * HH / (256 * 8), 256, 0, stream>>>(emb, embbf);
    init_misc<<<256, 256, 0, stream>>>(h0, hseq, ctr);
    lstm_persist<<<NWG, NTHR, LDS_TOTAL, stream>>>(x, emb, embbf, Wih, Whh,
                                                   bih, bhh, c0, hseq, ctr,
                                                   cached, embf);
    fc_kernel<<<BB, 128, 0, stream>>>(hseq + (size_t)(cached ? SS : 0) * BBHH,
                                      fcW, fcb, (float*)d_out);
}